// Round 9
// baseline (161.706 us; speedup 1.0000x reference)
//
#include <hip/hip_runtime.h>

#define EMB 512
#define HEADS 8
#define HD 64
#define NSEQ 4096
#define BATCH 2
#define WINDOW 128

typedef unsigned short u16;
typedef __attribute__((ext_vector_type(8))) short bf16x8;
typedef __attribute__((ext_vector_type(4))) float f32x4;

#define XS 4194304u   // x elems (2*4096*512)
#define WS 262144u    // one weight matrix elems
#define BS 512u       // one bias elems

__device__ __forceinline__ float bf2f(u16 u) {
    union { unsigned int i; float f; } x;
    x.i = ((unsigned int)u) << 16;
    return x.f;
}

__device__ __forceinline__ u16 f2bf(float f) {
    union { float f; unsigned int i; } x;
    x.f = f;
    unsigned int i = x.i;
    unsigned int lsb = (i >> 16) & 1u;
    i += 0x7fffu + lsb;   // round-to-nearest-even
    return (u16)(i >> 16);
}

struct raw8 { uint4 lo, hi; };

__device__ __forceinline__ raw8 loadraw8(const void* base, size_t off, int isbf) {
    raw8 r;
    if (isbf) {
        r.lo = *(const uint4*)((const u16*)base + off);
    } else {
        const float* f = (const float*)base + off;
        r.lo = *(const uint4*)f;
        r.hi = *(const uint4*)(f + 4);
    }
    return r;
}

__device__ __forceinline__ uint4 cvt8(const raw8& r, int isbf) {
    if (isbf) return r.lo;
    const float* a = (const float*)&r.lo;
    const float* b = (const float*)&r.hi;
    uint4 o;
    o.x = (unsigned)f2bf(a[0]) | ((unsigned)f2bf(a[1]) << 16);
    o.y = (unsigned)f2bf(a[2]) | ((unsigned)f2bf(a[3]) << 16);
    o.z = (unsigned)f2bf(b[0]) | ((unsigned)f2bf(b[1]) << 16);
    o.w = (unsigned)f2bf(b[2]) | ((unsigned)f2bf(b[3]) << 16);
    return o;
}

__device__ __forceinline__ int probe_bf16(const void* p) {
    const int lane = threadIdx.x & 63;
    u16 w = ((const u16*)p)[lane * 2];
    int e = (w >> 7) & 0xff;
    bool sane = (w == 0) || (e >= 100 && e <= 140);
    unsigned long long m = __ballot(sane);
    return __popcll(m) >= 48;
}

// ---------------------------------------------------------------------------
// Pre-pass (unchanged from R8): convert all params to bf16 in ws.
// ---------------------------------------------------------------------------
__global__ __launch_bounds__(256)
void prepass(const void* __restrict__ x,
             const void* __restrict__ Wq, const void* __restrict__ bq,
             const void* __restrict__ Wk, const void* __restrict__ bk,
             const void* __restrict__ Wv, const void* __restrict__ bv,
             const void* __restrict__ Wo, const void* __restrict__ bo,
             u16* __restrict__ xb, u16* __restrict__ wb, u16* __restrict__ bb,
             int* __restrict__ flags)
{
    const int fx  = probe_bf16(x);
    const int fwq = probe_bf16(Wq), fbq = probe_bf16(bq);
    const int fwk = probe_bf16(Wk), fbk = probe_bf16(bk);
    const int fwv = probe_bf16(Wv), fbv = probe_bf16(bv);
    const int fwo = probe_bf16(Wo), fbo = probe_bf16(bo);
    if (blockIdx.x == 0 && threadIdx.x == 0) flags[0] = fx;

    size_t idx = ((size_t)blockIdx.x * 256 + threadIdx.x) * 8;
    const size_t T_X = XS, T_W = XS + 4 * (size_t)WS, T_ALL = T_W + 4 * (size_t)BS;
    if (idx >= T_ALL) return;

    const void* src; int fl; u16* dst; size_t off;
    if (idx < T_X) {
        src = x; fl = fx; dst = xb; off = idx;
    } else if (idx < T_W) {
        size_t w = idx - T_X;
        int wi = (int)(w / WS); off = w % WS;
        src = (wi == 0) ? Wq : (wi == 1) ? Wk : (wi == 2) ? Wv : Wo;
        fl  = (wi == 0) ? fwq : (wi == 1) ? fwk : (wi == 2) ? fwv : fwo;
        dst = wb + (size_t)wi * WS;
    } else {
        size_t b = idx - T_W;
        int bi = (int)(b / BS); off = b % BS;
        src = (bi == 0) ? bq : (bi == 1) ? bk : (bi == 2) ? bv : bo;
        fl  = (bi == 0) ? fbq : (bi == 1) ? fbk : (bi == 2) ? fbv : fbo;
        dst = bb + (size_t)bi * BS;
    }
    *(uint4*)(dst + off) = cvt8(loadraw8(src, off, fl), fl);
}

// ---------------------------------------------------------------------------
// Fused QKV projection (R8 core). q,k -> [bh][n][64]; v -> TRANSPOSED
// [bh][d][n] via LDS-mediated transpose in the epilogue (coalesced writes).
// q pre-scaled by 1/sqrt(512). grid (64, 12).
// ---------------------------------------------------------------------------
#define TP 136   // transpose LDS pitch (u16); 272 B rows, 16B-aligned
__global__ __launch_bounds__(256)
void qkv_gemm(const u16* __restrict__ X, const u16* __restrict__ Wall,
              const u16* __restrict__ ball,
              u16* __restrict__ qo, u16* __restrict__ ko, u16* __restrict__ vo)
{
    __shared__ __align__(16) u16 SH[64 * TP];   // 17408 B; aliases As|Bs and T
    u16* As = SH;            // [0 .. 4095]
    u16* Bs = SH + 4096;     // [4096 .. 8191]

    const int tid  = threadIdx.x;
    const int wave = tid >> 6;
    const int lane = tid & 63;
    const int quad = lane >> 4;
    const int l16  = lane & 15;
    const int wm = wave >> 1, wn = wave & 1;

    const int m0 = blockIdx.x * 128;
    const int by = blockIdx.y;
    const int wsel = by >> 2;
    const int n0 = (by & 3) * 128;

    const u16* W  = Wall + (size_t)wsel * WS;
    const u16* bi = ball + (size_t)wsel * BS;
    u16* out      = (wsel == 0) ? qo : (wsel == 1) ? ko : vo;
    const float oscale = (wsel == 0) ? 0.04419417382415922f : 1.0f;

    f32x4 acc[4][4];
#pragma unroll
    for (int i = 0; i < 4; ++i)
#pragma unroll
        for (int j = 0; j < 4; ++j)
            acc[i][j] = (f32x4){0.f, 0.f, 0.f, 0.f};

    const int c1 = tid, c2 = tid + 256;
    const int r1 = c1 >> 2, k1 = (c1 & 3) * 8;
    const int r2 = c2 >> 2, k2 = (c2 & 3) * 8;

    uint4 a1 = *(const uint4*)(X + (size_t)(m0 + r1) * EMB + k1);
    uint4 a2 = *(const uint4*)(X + (size_t)(m0 + r2) * EMB + k2);
    uint4 b1 = *(const uint4*)(W + (size_t)(n0 + r1) * EMB + k1);
    uint4 b2 = *(const uint4*)(W + (size_t)(n0 + r2) * EMB + k2);

    for (int kt = 0; kt < 16; ++kt) {
        __syncthreads();
        *(uint4*)&As[c1 * 8] = a1;
        *(uint4*)&As[c2 * 8] = a2;
        *(uint4*)&Bs[c1 * 8] = b1;
        *(uint4*)&Bs[c2 * 8] = b2;
        __syncthreads();

        if (kt < 15) {
            const int kk0 = (kt + 1) * 32;
            a1 = *(const uint4*)(X + (size_t)(m0 + r1) * EMB + kk0 + k1);
            a2 = *(const uint4*)(X + (size_t)(m0 + r2) * EMB + kk0 + k2);
            b1 = *(const uint4*)(W + (size_t)(n0 + r1) * EMB + kk0 + k1);
            b2 = *(const uint4*)(W + (size_t)(n0 + r2) * EMB + kk0 + k2);
        }

        bf16x8 af[4], bfr[4];
#pragma unroll
        for (int i = 0; i < 4; ++i)
            af[i] = *(const bf16x8*)&As[(wm * 64 + i * 16 + l16) * 32 + quad * 8];
#pragma unroll
        for (int j = 0; j < 4; ++j)
            bfr[j] = *(const bf16x8*)&Bs[(wn * 64 + j * 16 + l16) * 32 + quad * 8];
#pragma unroll
        for (int i = 0; i < 4; ++i)
#pragma unroll
            for (int j = 0; j < 4; ++j)
                acc[i][j] = __builtin_amdgcn_mfma_f32_16x16x32_bf16(af[i], bfr[j], acc[i][j], 0, 0, 0);
    }

    if (wsel != 2) {
        // q/k epilogue: [bh][n][d]
#pragma unroll
        for (int j = 0; j < 4; ++j) {
            const int col = n0 + wn * 64 + j * 16 + l16;
            const float bv_ = bf2f(bi[col]);
            const int h = col >> 6, d = col & 63;
#pragma unroll
            for (int i = 0; i < 4; ++i) {
#pragma unroll
                for (int r = 0; r < 4; ++r) {
                    const int row = m0 + wm * 64 + i * 16 + quad * 4 + r;
                    const int b = row >> 12, n = row & 4095;
                    out[(((size_t)(b * HEADS + h) * NSEQ) + n) * HD + d] =
                        f2bf((acc[i][j][r] + bv_) * oscale);
                }
            }
        }
    } else {
        // v epilogue: transpose 128x128 tile through LDS, write [bh][d][n]
        const int b = m0 >> 12;
        const int nbase = m0 & 4095;
#pragma unroll
        for (int half = 0; half < 2; ++half) {
            __syncthreads();   // T (aliases As/Bs) free
            if (wn == half) {
#pragma unroll
                for (int j = 0; j < 4; ++j) {
                    const int col = n0 + wn * 64 + j * 16 + l16;
                    const float bv_ = bf2f(bi[col]);
                    const int cl = j * 16 + l16;               // 0..63 local col
#pragma unroll
                    for (int i = 0; i < 4; ++i)
#pragma unroll
                        for (int r = 0; r < 4; ++r) {
                            const int rowl = wm * 64 + i * 16 + quad * 4 + r; // 0..127
                            SH[cl * TP + rowl] = f2bf(acc[i][j][r] + bv_);
                        }
                }
            }
            __syncthreads();
            // write out: 64 cols x 128 n = 1024 uint4, 4 per thread
#pragma unroll
            for (int p = 0; p < 4; ++p) {
                const int idx  = tid + p * 256;       // 0..1023
                const int dcol = idx >> 4;            // local col 0..63
                const int nch  = (idx & 15) * 8;      // 0..120
                uint4 val = *(const uint4*)&SH[dcol * TP + nch];
                const int col = n0 + half * 64 + dcol;
                const int h = col >> 6, d = col & 63;
                *(uint4*)(out + ((size_t)((b * HEADS + h) * HD + d)) * NSEQ + nbase + nch) = val;
            }
        }
    }
}

// ---------------------------------------------------------------------------
// MFMA flash attention. q,k: [bh][n][64]; v: [bh][d][n] (pre-transposed).
// Staging is pure uint4 (zero LDS conflicts). grid (64, 16).
// ---------------------------------------------------------------------------
#define KP 72
__global__ __launch_bounds__(256)
void attn_mfma(const u16* __restrict__ q, const u16* __restrict__ k,
               const u16* __restrict__ v, u16* __restrict__ ao)
{
    __shared__ __align__(16) u16 Ks[64 * KP];      // [key][d]
    __shared__ __align__(16) u16 Vt[64 * KP];      // [d][key]
    __shared__ __align__(16) u16 Pb[4][16 * KP];   // per-wave P [q][key]

    const int tid  = threadIdx.x;
    const int wave = tid >> 6;
    const int lane = tid & 63;
    const int quad = lane >> 4;
    const int l16  = lane & 15;

    const int bh = blockIdx.y;
    const int q0 = blockIdx.x * 64;
    const int qw = q0 + wave * 16;
    const size_t base = (size_t)bh * NSEQ * HD;    // valid for q,k [n][d] and v [d][n]

    bf16x8 qa0 = *(const bf16x8*)(q + base + (size_t)(qw + l16) * HD + quad * 8);
    bf16x8 qa1 = *(const bf16x8*)(q + base + (size_t)(qw + l16) * HD + 32 + quad * 8);

    f32x4 O[4];
    float m_run[4], l_run[4];
#pragma unroll
    for (int t = 0; t < 4; ++t) O[t] = (f32x4){0.f, 0.f, 0.f, 0.f};
#pragma unroll
    for (int r = 0; r < 4; ++r) { m_run[r] = -1e30f; l_run[r] = 0.f; }

    // staging geometry: K: key=idx>>3, d-chunk=(idx&7)*8 ; V: d=idx>>3, key-chunk=(idx&7)*8
    const int row_s[2] = { tid >> 3, (tid + 256) >> 3 };
    const int ch8      = (tid & 7) * 8;

    uint4 pkv[2], pvv[2];
    {
        const int kbase = q0 - 128;
        const int koff  = (kbase < 0) ? 0 : (kbase > NSEQ - 64 ? NSEQ - 64 : kbase);
#pragma unroll
        for (int s = 0; s < 2; ++s) {
            int kg = kbase + row_s[s];
            kg = (kg < 0) ? 0 : (kg > NSEQ - 1 ? NSEQ - 1 : kg);
            pkv[s] = *(const uint4*)(k + base + (size_t)kg * HD + ch8);
            pvv[s] = *(const uint4*)(v + base + (size_t)row_s[s] * NSEQ + koff + ch8);
        }
    }

    for (int c = 0; c < 5; ++c) {
        const int kbase = q0 - 128 + c * 64;

        __syncthreads();
#pragma unroll
        for (int s = 0; s < 2; ++s) {
            *(uint4*)&Ks[row_s[s] * KP + ch8] = pkv[s];
            *(uint4*)&Vt[row_s[s] * KP + ch8] = pvv[s];
        }
        __syncthreads();

        if (c < 4) {
            const int kb2  = kbase + 64;
            const int koff = (kb2 < 0) ? 0 : (kb2 > NSEQ - 64 ? NSEQ - 64 : kb2);
#pragma unroll
            for (int s = 0; s < 2; ++s) {
                int kg = kb2 + row_s[s];
                kg = (kg < 0) ? 0 : (kg > NSEQ - 1 ? NSEQ - 1 : kg);
                pkv[s] = *(const uint4*)(k + base + (size_t)kg * HD + ch8);
                pvv[s] = *(const uint4*)(v + base + (size_t)row_s[s] * NSEQ + koff + ch8);
            }
        }

        // ---- QK^T ----
        f32x4 sv[4];
#pragma unroll
        for (int t = 0; t < 4; ++t) {
            bf16x8 b0 = *(const bf16x8*)&Ks[(t * 16 + l16) * KP + quad * 8];
            bf16x8 b1 = *(const bf16x8*)&Ks[(t * 16 + l16) * KP + 32 + quad * 8];
            f32x4 sacc = (f32x4){0.f, 0.f, 0.f, 0.f};
            sacc = __builtin_amdgcn_mfma_f32_16x16x32_bf16(qa0, b0, sacc, 0, 0, 0);
            sacc = __builtin_amdgcn_mfma_f32_16x16x32_bf16(qa1, b1, sacc, 0, 0, 0);
            sv[t] = sacc;
        }

        // ---- band mask (kills OOB, clamped, and garbage columns) ----
#pragma unroll
        for (int t = 0; t < 4; ++t) {
            const int jg = kbase + t * 16 + l16;
            const bool jok = ((unsigned)jg) < (unsigned)NSEQ;
#pragma unroll
            for (int r = 0; r < 4; ++r) {
                const int iq = qw + quad * 4 + r;
                const bool band = ((unsigned)(iq - jg + WINDOW)) <= (unsigned)(2 * WINDOW);
                if (!(jok && band)) sv[t][r] = -1e30f;
            }
        }

        // ---- online softmax ----
        float mnew[4];
#pragma unroll
        for (int r = 0; r < 4; ++r)
            mnew[r] = fmaxf(fmaxf(sv[0][r], sv[1][r]), fmaxf(sv[2][r], sv[3][r]));
#pragma unroll
        for (int off = 1; off < 16; off <<= 1)
#pragma unroll
            for (int r = 0; r < 4; ++r)
                mnew[r] = fmaxf(mnew[r], __shfl_xor(mnew[r], off, 64));

        float alpha[4], mi[4];
#pragma unroll
        for (int r = 0; r < 4; ++r) {
            mi[r] = fmaxf(m_run[r], mnew[r]);
            alpha[r] = __expf(m_run[r] - mi[r]);
            m_run[r] = mi[r];
        }

        float p[4][4], lnew[4] = {0.f, 0.f, 0.f, 0.f};
#pragma unroll
        for (int t = 0; t < 4; ++t)
#pragma unroll
            for (int r = 0; r < 4; ++r) {
                float pv = (sv[t][r] > -1e29f) ? __expf(sv[t][r] - mi[r]) : 0.f;
                p[t][r] = pv;
                lnew[r] += pv;
            }
#pragma unroll
        for (int off = 1; off < 16; off <<= 1)
#pragma unroll
            for (int r = 0; r < 4; ++r)
                lnew[r] += __shfl_xor(lnew[r], off, 64);
#pragma unroll
        for (int r = 0; r < 4; ++r)
            l_run[r] = l_run[r] * alpha[r] + lnew[r];

#pragma unroll
        for (int t = 0; t < 4; ++t)
#pragma unroll
            for (int r = 0; r < 4; ++r)
                O[t][r] *= alpha[r];

        // ---- P -> LDS (C-layout), read back A-layout ----
#pragma unroll
        for (int t = 0; t < 4; ++t)
#pragma unroll
            for (int r = 0; r < 4; ++r)
                Pb[wave][(quad * 4 + r) * KP + t * 16 + l16] = f2bf(p[t][r]);

        // ---- PV ----
#pragma unroll
        for (int ks = 0; ks < 2; ++ks) {
            bf16x8 pa = *(const bf16x8*)&Pb[wave][l16 * KP + ks * 32 + quad * 8];
#pragma unroll
            for (int t = 0; t < 4; ++t) {
                bf16x8 vb = *(const bf16x8*)&Vt[(t * 16 + l16) * KP + ks * 32 + quad * 8];
                O[t] = __builtin_amdgcn_mfma_f32_16x16x32_bf16(pa, vb, O[t], 0, 0, 0);
            }
        }
    }

    const int bb = bh >> 3, hh = bh & 7;
    float rl[4];
#pragma unroll
    for (int r = 0; r < 4; ++r) rl[r] = 1.f / l_run[r];
#pragma unroll
    for (int t = 0; t < 4; ++t)
#pragma unroll
        for (int r = 0; r < 4; ++r) {
            const int iq = qw + quad * 4 + r;
            ao[((size_t)(bb * NSEQ + iq)) * EMB + hh * HD + t * 16 + l16] =
                f2bf(O[t][r] * rl[r]);
        }
}

// ---------------------------------------------------------------------------
// Output projection (unchanged from R8). grid (64, 4).
// ---------------------------------------------------------------------------
__global__ __launch_bounds__(256)
void out_gemm(const u16* __restrict__ A, const u16* __restrict__ W,
              const u16* __restrict__ bias, void* __restrict__ out,
              const int* __restrict__ flags)
{
    __shared__ __align__(16) u16 As[128 * 32];
    __shared__ __align__(16) u16 Bs[128 * 32];

    const int tid  = threadIdx.x;
    const int wave = tid >> 6;
    const int lane = tid & 63;
    const int quad = lane >> 4;
    const int l16  = lane & 15;
    const int wm = wave >> 1, wn = wave & 1;

    const int m0 = blockIdx.x * 128;
    const int n0 = blockIdx.y * 128;
    const int fo = flags[0];

    f32x4 acc[4][4];
#pragma unroll
    for (int i = 0; i < 4; ++i)
#pragma unroll
        for (int j = 0; j < 4; ++j)
            acc[i][j] = (f32x4){0.f, 0.f, 0.f, 0.f};

    const int c1 = tid, c2 = tid + 256;
    const int r1 = c1 >> 2, k1 = (c1 & 3) * 8;
    const int r2 = c2 >> 2, k2 = (c2 & 3) * 8;

    uint4 a1 = *(const uint4*)(A + (size_t)(m0 + r1) * EMB + k1);
    uint4 a2 = *(const uint4*)(A + (size_t)(m0 + r2) * EMB + k2);
    uint4 b1 = *(const uint4*)(W + (size_t)(n0 + r1) * EMB + k1);
    uint4 b2 = *(const uint4*)(W + (size_t)(n0 + r2) * EMB + k2);

    for (int kt = 0; kt < 16; ++kt) {
        __syncthreads();
        *(uint4*)&As[c1 * 8] = a1;
        *(uint4*)&As[c2 * 8] = a2;
        *(uint4*)&Bs[c1 * 8] = b1;
        *(uint4*)&Bs[c2 * 8] = b2;
        __syncthreads();

        if (kt < 15) {
            const int kk0 = (kt + 1) * 32;
            a1 = *(const uint4*)(A + (size_t)(m0 + r1) * EMB + kk0 + k1);
            a2 = *(const uint4*)(A + (size_t)(m0 + r2) * EMB + kk0 + k2);
            b1 = *(const uint4*)(W + (size_t)(n0 + r1) * EMB + kk0 + k1);
            b2 = *(const uint4*)(W + (size_t)(n0 + r2) * EMB + kk0 + k2);
        }

        bf16x8 af[4], bfr[4];
#pragma unroll
        for (int i = 0; i < 4; ++i)
            af[i] = *(const bf16x8*)&As[(wm * 64 + i * 16 + l16) * 32 + quad * 8];
#pragma unroll
        for (int j = 0; j < 4; ++j)
            bfr[j] = *(const bf16x8*)&Bs[(wn * 64 + j * 16 + l16) * 32 + quad * 8];
#pragma unroll
        for (int i = 0; i < 4; ++i)
#pragma unroll
            for (int j = 0; j < 4; ++j)
                acc[i][j] = __builtin_amdgcn_mfma_f32_16x16x32_bf16(af[i], bfr[j], acc[i][j], 0, 0, 0);
    }

#pragma unroll
    for (int j = 0; j < 4; ++j) {
        const int col = n0 + wn * 64 + j * 16 + l16;
        const float bv_ = bf2f(bias[col]);
#pragma unroll
        for (int i = 0; i < 4; ++i) {
#pragma unroll
            for (int r = 0; r < 4; ++r) {
                const int row = m0 + wm * 64 + i * 16 + quad * 4 + r;
                const float val = acc[i][j][r] + bv_;
                const size_t idx = (size_t)row * EMB + col;
                if (fo) ((u16*)out)[idx] = f2bf(val);
                else    ((float*)out)[idx] = val;
            }
        }
    }
}

extern "C" void kernel_launch(void* const* d_in, const int* in_sizes, int n_in,
                              void* d_out, int out_size, void* d_ws, size_t ws_size,
                              hipStream_t stream)
{
    const size_t HSZ  = (size_t)BATCH * HEADS * NSEQ * HD;   // 4.19M elems
    char* base = (char*)d_ws;
    int* flags = (int*)base;
    const size_t off = 256;

    u16* xb = (u16*)(base + off);            // 4.19M elems
    u16* wb = xb + XS;                       // 4 * 262144
    u16* bb = wb + 4 * (size_t)WS;           // 4 * 512
    u16* kk = bb + 4 * (size_t)BS;           // k
    u16* vv = kk + HSZ;                      // v (transposed [bh][d][n])
    u16* ao = vv + HSZ;                      // ao
    u16* qq = ao + HSZ;                      // q (tier-1)

    const size_t need_t1 = off + 2 * (XS + 4 * (size_t)WS + 4 * (size_t)BS + 4 * HSZ);
    if (ws_size < need_t1) {
        qq = (u16*)d_out;                    // q dead before out_gemm writes d_out
    }

    prepass<<<dim3(2561), 256, 0, stream>>>(d_in[0], d_in[1], d_in[2], d_in[3],
                                            d_in[4], d_in[5], d_in[6], d_in[7],
                                            d_in[8], xb, wb, bb, flags);
    qkv_gemm<<<dim3(64, 12), 256, 0, stream>>>(xb, wb, bb, qq, kk, vv);
    attn_mfma<<<dim3(64, 16), 256, 0, stream>>>(qq, kk, vv, ao);
    out_gemm<<<dim3(64, 4), 256, 0, stream>>>(ao, wb + 3 * (size_t)WS, bb + 3 * (size_t)BS,
                                              d_out, flags);
}